// Round 1
// baseline (356.947 us; speedup 1.0000x reference)
//
#include <hip/hip_runtime.h>

// Problem constants (from reference setup_inputs):
//   x:   [B=8, C=16, H=512, W=512] float32
//   phi: [B=8, 2,    H=512, W=512] float32  (disp[...,0]=dy from phi[:,0], [...,1]=dx from phi[:,1])
//   out: [B, C, H, W] float32
// Bilinear pull with wrap (circulant) boundary. H, W are powers of two -> mod == & (N-1).

constexpr int B = 8, C = 16, H = 512, W = 512;
constexpr int HW = H * W;

__global__ __launch_bounds__(256) void pull_wrap_kernel(const float* __restrict__ x,
                                                        const float* __restrict__ phi,
                                                        float* __restrict__ out) {
    int idx = blockIdx.x * blockDim.x + threadIdx.x;  // over B*H*W
    if (idx >= B * HW) return;
    int b  = idx >> 18;            // / (512*512)
    int hw = idx & (HW - 1);
    int h  = hw >> 9;              // / 512
    int w  = hw & (W - 1);

    // phi[b,0,h,w] = dy, phi[b,1,h,w] = dx  (coalesced: consecutive threads -> consecutive hw)
    const float* phib = phi + (size_t)b * 2 * HW;
    float cy = phib[hw]      + (float)h;
    float cx = phib[HW + hw] + (float)w;

    float y0f = floorf(cy);
    float x0f = floorf(cx);
    float wy  = cy - y0f;
    float wx  = cx - x0f;

    int y0 = ((int)y0f) & (H - 1);
    int x0 = ((int)x0f) & (W - 1);
    int y1 = (y0 + 1)   & (H - 1);
    int x1 = (x0 + 1)   & (W - 1);

    int o00 = y0 * W + x0;
    int o01 = y0 * W + x1;
    int o10 = y1 * W + x0;
    int o11 = y1 * W + x1;

    float omwx = 1.0f - wx;
    float omwy = 1.0f - wy;

    const float* plane = x   + (size_t)b * C * HW;   // channel 0 plane for this batch
    float*       outp  = out + (size_t)b * C * HW + hw;

#pragma unroll
    for (int c = 0; c < C; ++c) {
        float v00 = plane[o00];
        float v01 = plane[o01];
        float v10 = plane[o10];
        float v11 = plane[o11];
        float top = v00 * omwx + v01 * wx;
        float bot = v10 * omwx + v11 * wx;
        outp[(size_t)c * HW] = top * omwy + bot * wy;
        plane += HW;
    }
}

extern "C" void kernel_launch(void* const* d_in, const int* in_sizes, int n_in,
                              void* d_out, int out_size, void* d_ws, size_t ws_size,
                              hipStream_t stream) {
    const float* x   = (const float*)d_in[0];
    const float* phi = (const float*)d_in[1];
    float* out = (float*)d_out;

    int n = B * HW;                       // one thread per (b,h,w)
    dim3 block(256);
    dim3 grid((n + 255) / 256);
    pull_wrap_kernel<<<grid, block, 0, stream>>>(x, phi, out);
}